// Round 11
// baseline (276.462 us; speedup 1.0000x reference)
//
#include <hip/hip_runtime.h>
#include <hip/hip_bf16.h>

// GATNet v18: 8-way privatized histogram. v17 unmasked the merged
// gemm1+hist kernel at 63-66us with MfmaUtil 3.5%/VALU 7.6% — pure atomic
// serialization (avg 16 same-address RMW chains per dst). deg split into
// 8 copies (copy = histBlock&7) -> per-address contention 16->2. Scatter
// recomputes the copy from edge index; k_scan sums copies and emits
// per-copy absolute sub-offsets absoff[v*8+c] (32B/node, coalesced).

#define LRELU(x) ((x) > 0.f ? (x) : 0.2f * (x))

typedef __attribute__((ext_vector_type(8))) short short8;
typedef __attribute__((ext_vector_type(8))) unsigned short ushort8;
typedef __attribute__((ext_vector_type(4))) float f32x4;

__device__ inline unsigned short f2b(float f) {
    __hip_bfloat16 h = __float2bfloat16(f);
    return *reinterpret_cast<unsigned short*>(&h);
}
__device__ inline float b2f(unsigned short u) {
    __hip_bfloat16 h;
    *reinterpret_cast<unsigned short*>(&h) = u;
    return __bfloat162float(h);
}
__device__ inline float bl(unsigned int u) { return __uint_as_float(u << 16); }
__device__ inline float bh(unsigned int u) { return __uint_as_float(u & 0xffff0000u); }

// ---------------- weight prep (standalone, tiny, must precede gemm1) -------

__global__ __launch_bounds__(256) void k_prep(const float* __restrict__ W1,
                                              const float* __restrict__ W2,
                                              unsigned short* __restrict__ W1t,
                                              unsigned short* __restrict__ W2t) {
    int b = blockIdx.x;
    if (b < 256) {
        int k = b, nn = threadIdx.x;
        W1t[nn * 256 + k] = f2b(W1[k * 256 + nn]);
    } else {
        int nn = b - 256, k = threadIdx.x;
        W2t[nn * 256 + k] = f2b(W2[k * 16 + nn]);
    }
}

// ---------------- fused single-kernel scan over 8-copy histogram -----------
// Reads deg8[c][v] c=0..7, total=sum+1 (self loop). Cross-block prefix via
// flag|value publish (v15 protocol, verified). Writes offs[v] and per-copy
// absolute sub-offsets absoff[v*8+c].

__global__ __launch_bounds__(256) void k_scan(const int* __restrict__ deg8,
                                              unsigned int* __restrict__ state,
                                              int* __restrict__ offs,
                                              int* __restrict__ absoff, int n, int P) {
    __shared__ int sc[256];
    __shared__ int sa[256];
    int b = blockIdx.x, t = threadIdx.x;
    int i = b * 256 + t;
    int d8[8];
    int tot = 0;
    if (i < n) {
#pragma unroll
        for (int c = 0; c < 8; c++) {
            d8[c] = deg8[c * n + i];
            tot += d8[c];
        }
        tot += 1;   // self loop
    }
    sc[t] = tot;
    __syncthreads();
    for (int off = 1; off < 256; off <<= 1) {
        int x = 0;
        if (t >= off) x = sc[t - off];
        __syncthreads();
        sc[t] += x;
        __syncthreads();
    }
    if (t == 255) {
        unsigned int pack = 0x80000000u | (unsigned int)sc[255];
        atomicExch(&state[b], pack);   // device-scope publish (flag+value, one word)
    }
    if (t < b) {
        unsigned int s;
        do {
            s = atomicAdd(&state[t], 0u);
        } while (!(s & 0x80000000u));
        sa[t] = (int)(s & 0x7fffffffu);
    } else {
        sa[t] = 0;
    }
    __syncthreads();
    for (int off = 128; off; off >>= 1) {
        if (t < off) sa[t] += sa[t + off];
        __syncthreads();
    }
    int prefix = sa[0];
    if (i < n) {
        int myoff = prefix + sc[t] - tot;   // exclusive
        offs[i] = myoff;
        int run = myoff;
        int ab[8];
#pragma unroll
        for (int c = 0; c < 8; c++) {
            ab[c] = run;
            run += d8[c];
        }
        int4* ap = (int4*)(absoff + (size_t)i * 8);
        ap[0] = make_int4(ab[0], ab[1], ab[2], ab[3]);
        ap[1] = make_int4(ab[4], ab[5], ab[6], ab[7]);
    }
    if (i == 0) offs[n] = P;
}

// ---------------- scatter (atomic-free; copy recomputed from edge index) ----

__global__ void k_scatter(const int* __restrict__ src, const int* __restrict__ dst,
                          const int* __restrict__ pos, const int* __restrict__ offs,
                          const int* __restrict__ absoff,
                          int* __restrict__ csr, int E, int n) {
    int i = blockIdx.x * 256 + threadIdx.x;
    if (i < E) {
        int d = dst[i];
        int c = (i >> 8) & 7;   // same formula as hist branch (bb = i>>8)
        csr[absoff[(size_t)d * 8 + c] + pos[i]] = src[i];
    } else if (i < E + n) {
        int v = i - E;
        csr[offs[v + 1] - 1] = v;   // self loop in the last slot of row v
    }
}

// ---------------- GEMM1 (+al1 fused) MERGED with privatized hist -----------
// Blocks [0, GB): gemm1 128x128 tile (+fused logits). Blocks [GB, GB+HB):
// hist into deg8[bb&7][dst] (8-way contention split).

__global__ __launch_bounds__(256) void k_gemm1h(const float* __restrict__ A,
                                                const unsigned short* __restrict__ Wt,
                                                const float* __restrict__ asrc,
                                                const float* __restrict__ adst,
                                                unsigned short* __restrict__ h1b,
                                                float* __restrict__ als,
                                                float* __restrict__ ald, int M,
                                                const int* __restrict__ dst,
                                                int* deg8, int* __restrict__ pos,
                                                int E, int GB, int GX) {
    __shared__ unsigned short As[128][40];
    __shared__ unsigned short Bs[128][40];
    int b = blockIdx.x;
    if (b >= GB) {
        // ---- hist branch (privatized) ----
        int bb = b - GB;
        int i = bb * 256 + threadIdx.x;
        if (i < E) {
            int d = dst[i];
            int c = bb & 7;
            pos[i] = atomicAdd(&deg8[c * M + d], 1);
        }
        return;
    }
    // ---- gemm1 branch ----
    int t = threadIdx.x;
    int bx = b % GX, by = b / GX;
    int r0 = bx * 128, c0 = by * 128;
    int srow = t >> 1, shalf = t & 1;
    int lane = t & 63, w = t >> 6;
    int lane15 = lane & 15, quad = lane >> 4;
    int rbw = (w & 1) * 64, cbw = (w >> 1) * 64;

    f32x4 acc[4][4];
#pragma unroll
    for (int i = 0; i < 4; i++)
#pragma unroll
        for (int j = 0; j < 4; j++) acc[i][j] = (f32x4)0.f;

    for (int k0 = 0; k0 < 256; k0 += 32) {
        {
            int row = r0 + srow;
            ushort8 p0, p1;
            if (row < M) {
                const float4* sp = (const float4*)&A[(size_t)row * 256 + k0 + shalf * 16];
                float4 f0 = sp[0], f1 = sp[1], f2 = sp[2], f3 = sp[3];
                p0[0] = f2b(f0.x); p0[1] = f2b(f0.y); p0[2] = f2b(f0.z); p0[3] = f2b(f0.w);
                p0[4] = f2b(f1.x); p0[5] = f2b(f1.y); p0[6] = f2b(f1.z); p0[7] = f2b(f1.w);
                p1[0] = f2b(f2.x); p1[1] = f2b(f2.y); p1[2] = f2b(f2.z); p1[3] = f2b(f2.w);
                p1[4] = f2b(f3.x); p1[5] = f2b(f3.y); p1[6] = f2b(f3.z); p1[7] = f2b(f3.w);
            } else {
                p0 = (ushort8)0; p1 = (ushort8)0;
            }
            *(ushort8*)&As[srow][shalf * 16] = p0;
            *(ushort8*)&As[srow][shalf * 16 + 8] = p1;
            const ushort8* bp = (const ushort8*)&Wt[(size_t)(c0 + srow) * 256 + k0 + shalf * 16];
            *(ushort8*)&Bs[srow][shalf * 16] = bp[0];
            *(ushort8*)&Bs[srow][shalf * 16 + 8] = bp[1];
        }
        __syncthreads();
        short8 af[4], bf[4];
#pragma unroll
        for (int i = 0; i < 4; i++)
            af[i] = *(const short8*)&As[rbw + i * 16 + lane15][quad * 8];
#pragma unroll
        for (int j = 0; j < 4; j++)
            bf[j] = *(const short8*)&Bs[cbw + j * 16 + lane15][quad * 8];
#pragma unroll
        for (int i = 0; i < 4; i++)
#pragma unroll
            for (int j = 0; j < 4; j++)
                acc[i][j] = __builtin_amdgcn_mfma_f32_16x16x32_bf16(af[i], bf[j], acc[i][j], 0, 0, 0);
        __syncthreads();
    }
    // h1b store
#pragma unroll
    for (int i = 0; i < 4; i++) {
        int rowb = r0 + rbw + i * 16 + quad * 4;
#pragma unroll
        for (int j = 0; j < 4; j++) {
            int col = c0 + cbw + j * 16 + lane15;
#pragma unroll
            for (int r = 0; r < 4; r++) {
                int row = rowb + r;
                if (row < M) h1b[(size_t)row * 256 + col] = f2b(acc[i][j][r]);
            }
        }
    }
    // fused attention logits: 2 heads per wave-col-span
    float asv[4], adv[4];
#pragma unroll
    for (int j = 0; j < 4; j++) {
        asv[j] = asrc[c0 + cbw + j * 16 + lane15];
        adv[j] = adst[c0 + cbw + j * 16 + lane15];
    }
    int hbase = (c0 + cbw) >> 5;
#pragma unroll
    for (int i = 0; i < 4; i++) {
#pragma unroll
        for (int r = 0; r < 4; r++) {
            int row = r0 + rbw + i * 16 + quad * 4 + r;
            float ps0 = acc[i][0][r] * asv[0] + acc[i][1][r] * asv[1];
            float pd0 = acc[i][0][r] * adv[0] + acc[i][1][r] * adv[1];
            float ps1 = acc[i][2][r] * asv[2] + acc[i][3][r] * asv[3];
            float pd1 = acc[i][2][r] * adv[2] + acc[i][3][r] * adv[3];
#pragma unroll
            for (int off = 1; off < 16; off <<= 1) {
                ps0 += __shfl_xor(ps0, off, 16);
                pd0 += __shfl_xor(pd0, off, 16);
                ps1 += __shfl_xor(ps1, off, 16);
                pd1 += __shfl_xor(pd1, off, 16);
            }
            if (lane15 == 0 && row < M) {
                als[(size_t)row * 8 + hbase] = ps0;
                ald[(size_t)row * 8 + hbase] = pd0;
                als[(size_t)row * 8 + hbase + 1] = ps1;
                ald[(size_t)row * 8 + hbase + 1] = pd1;
            }
        }
    }
}

// ---------------- layer-1 aggregate: self-service weights (roofline) --------
// Split into two half-grid dispatches (v0 offset) for top-5 visibility.

__global__ __launch_bounds__(256) void k_agg1(const int* __restrict__ csr,
                                              const int* __restrict__ offs,
                                              const float* __restrict__ als,
                                              const float* __restrict__ aldg,
                                              const unsigned short* __restrict__ h1b,
                                              const float* __restrict__ b1,
                                              unsigned short* __restrict__ x2b,
                                              int v0, int vend) {
    int wid = threadIdx.x >> 6;
    int v = v0 + blockIdx.x * 4 + wid;
    if (v >= vend) return;
    int lane = threadIdx.x & 63;
    int h = lane >> 3;
    int start = __builtin_amdgcn_readfirstlane(offs[v]);
    int deg = __builtin_amdgcn_readfirstlane(offs[v + 1]) - start;
    const int* __restrict__ cp = csr + start;
    int dm1 = deg - 1;
    float aldvh = aldg[(size_t)v * 8 + h];
    float a0 = 0.f, a1 = 0.f, a2 = 0.f, a3 = 0.f, wsum = 0.f;
    for (int e = 0; e < deg; e += 4) {
        int u0 = cp[e];                  // e < deg always
        int u1 = cp[min(e + 1, dm1)];
        int u2 = cp[min(e + 2, dm1)];
        int u3 = cp[min(e + 3, dm1)];
        uint2 p0 = ((const uint2*)(h1b + (size_t)u0 * 256))[lane];
        uint2 p1 = ((const uint2*)(h1b + (size_t)u1 * 256))[lane];
        uint2 p2 = ((const uint2*)(h1b + (size_t)u2 * 256))[lane];
        uint2 p3 = ((const uint2*)(h1b + (size_t)u3 * 256))[lane];
        float x0 = als[u0 * 8 + h];
        float x1 = als[u1 * 8 + h];
        float x2 = als[u2 * 8 + h];
        float x3 = als[u3 * 8 + h];
        float w0 = __expf(LRELU(x0 + aldvh));
        float w1 = __expf(LRELU(x1 + aldvh));
        float w2 = __expf(LRELU(x2 + aldvh));
        float w3 = __expf(LRELU(x3 + aldvh));
        if (e + 1 > dm1) w1 = 0.f;
        if (e + 2 > dm1) w2 = 0.f;
        if (e + 3 > dm1) w3 = 0.f;
        a0 += w0 * bl(p0.x); a1 += w0 * bh(p0.x);
        a2 += w0 * bl(p0.y); a3 += w0 * bh(p0.y);
        a0 += w1 * bl(p1.x); a1 += w1 * bh(p1.x);
        a2 += w1 * bl(p1.y); a3 += w1 * bh(p1.y);
        a0 += w2 * bl(p2.x); a1 += w2 * bh(p2.x);
        a2 += w2 * bl(p2.y); a3 += w2 * bh(p2.y);
        a0 += w3 * bl(p3.x); a1 += w3 * bh(p3.x);
        a2 += w3 * bl(p3.y); a3 += w3 * bh(p3.y);
        wsum += (w0 + w1) + (w2 + w3);
    }
    float inv = 1.0f / wsum;
    float4 bb = ((const float4*)b1)[lane];
    float o0 = fmaxf(a0 * inv + bb.x, 0.f);
    float o1 = fmaxf(a1 * inv + bb.y, 0.f);
    float o2 = fmaxf(a2 * inv + bb.z, 0.f);
    float o3 = fmaxf(a3 * inv + bb.w, 0.f);
    uint2 o;
    o.x = (unsigned int)f2b(o0) | ((unsigned int)f2b(o1) << 16);
    o.y = (unsigned int)f2b(o2) | ((unsigned int)f2b(o3) << 16);
    ((uint2*)(x2b + (size_t)v * 256))[lane] = o;
}

// ---------------- GEMM2 (MFMA) + fused layer-2 logits ----------------------

__global__ __launch_bounds__(256) void k_gemm2(const unsigned short* __restrict__ Xb,
                                               const unsigned short* __restrict__ W2t,
                                               const float* __restrict__ asrc,
                                               const float* __restrict__ adst,
                                               unsigned short* __restrict__ h2b,
                                               float* __restrict__ als,
                                               float* __restrict__ ald, int n) {
    int t = threadIdx.x;
    int lane = t & 63, w = t >> 6;
    int lane15 = lane & 15, quad = lane >> 4;
    int row0 = blockIdx.x * 64 + w * 16;
    f32x4 acc = (f32x4)0.f;
#pragma unroll
    for (int k0 = 0; k0 < 256; k0 += 32) {
        short8 a = *(const short8*)&Xb[(size_t)(row0 + lane15) * 256 + k0 + quad * 8];
        short8 b = *(const short8*)&W2t[lane15 * 256 + k0 + quad * 8];
        acc = __builtin_amdgcn_mfma_f32_16x16x32_bf16(a, b, acc, 0, 0, 0);
    }
    float asv = asrc[lane15], adv = adst[lane15];
#pragma unroll
    for (int r = 0; r < 4; r++) {
        int row = row0 + quad * 4 + r;
        float hv = acc[r];
        float ps = hv * asv, pd = hv * adv;
#pragma unroll
        for (int off = 1; off < 16; off <<= 1) {
            ps += __shfl_xor(ps, off, 16);
            pd += __shfl_xor(pd, off, 16);
        }
        if (row < n) {
            h2b[(size_t)row * 16 + lane15] = f2b(hv);
            if (lane15 == 0) {
                als[row] = ps;
                ald[row] = pd;
            }
        }
    }
}

// ---------------- layer-2 aggregate: shfl-broadcast weights -----------------

__global__ __launch_bounds__(256) void k_agg2(const int* __restrict__ csr,
                                              const int* __restrict__ offs,
                                              const float* __restrict__ als,
                                              const float* __restrict__ aldg,
                                              const unsigned short* __restrict__ h2b,
                                              const float* __restrict__ b2,
                                              float* __restrict__ out, int n) {
    int wid = threadIdx.x >> 6;
    int v = blockIdx.x * 4 + wid;
    if (v >= n) return;
    int lane = threadIdx.x & 63;
    int slot = lane & 15, cq = lane >> 4;
    int start = __builtin_amdgcn_readfirstlane(offs[v]);
    int deg = __builtin_amdgcn_readfirstlane(offs[v + 1]) - start;
    int dm1 = deg - 1;
    float aldv = aldg[v];
    float a0 = 0.f, a1 = 0.f, a2 = 0.f, a3 = 0.f, wsum = 0.f;
    for (int e = 0; e < deg; e += 32) {
        int l32 = lane & 31;
        int idx = min(e + l32, dm1);
        int uu = csr[start + idx];
        float ww = __expf(LRELU(als[uu] + aldv));
        if (e + l32 > dm1) ww = 0.f;
#pragma unroll
        for (int k = 0; k < 2; k++) {
            int sl = k * 16 + slot;
            int ue = __shfl(uu, sl, 64);
            float we = __shfl(ww, sl, 64);
            uint2 pk = ((const uint2*)(h2b + (size_t)ue * 16))[cq];
            a0 += we * bl(pk.x);
            a1 += we * bh(pk.x);
            a2 += we * bl(pk.y);
            a3 += we * bh(pk.y);
            wsum += we;
        }
    }
#pragma unroll
    for (int off = 1; off < 16; off <<= 1) {
        a0 += __shfl_xor(a0, off, 64);
        a1 += __shfl_xor(a1, off, 64);
        a2 += __shfl_xor(a2, off, 64);
        a3 += __shfl_xor(a3, off, 64);
        wsum += __shfl_xor(wsum, off, 64);
    }
    float inv = 1.0f / wsum;
    float4 bb = ((const float4*)b2)[cq];
    float o0 = a0 * inv + bb.x;
    float o1 = a1 * inv + bb.y;
    float o2 = a2 * inv + bb.z;
    float o3 = a3 * inv + bb.w;
    float mx = fmaxf(fmaxf(o0, o1), fmaxf(o2, o3));
    mx = fmaxf(mx, __shfl_xor(mx, 16, 64));
    mx = fmaxf(mx, __shfl_xor(mx, 32, 64));
    float s = __expf(o0 - mx) + __expf(o1 - mx) + __expf(o2 - mx) + __expf(o3 - mx);
    s += __shfl_xor(s, 16, 64);
    s += __shfl_xor(s, 32, 64);
    float l = mx + __logf(s);
    if (slot == 0) {
        float4 r;
        r.x = o0 - l;
        r.y = o1 - l;
        r.z = o2 - l;
        r.w = o3 - l;
        ((float4*)out)[(size_t)v * 4 + cq] = r;
    }
}

// ---------------- launch ----------------

extern "C" void kernel_launch(void* const* d_in, const int* in_sizes, int n_in,
                              void* d_out, int out_size, void* d_ws, size_t ws_size,
                              hipStream_t stream) {
    const float* x = (const float*)d_in[0];
    const int* ei = (const int*)d_in[1];
    const float* W1 = (const float*)d_in[2];
    const float* asrc1 = (const float*)d_in[3];
    const float* adst1 = (const float*)d_in[4];
    const float* b1 = (const float*)d_in[5];
    const float* W2 = (const float*)d_in[6];
    const float* asrc2 = (const float*)d_in[7];
    const float* adst2 = (const float*)d_in[8];
    const float* b2 = (const float*)d_in[9];
    float* out = (float*)d_out;

    int n = in_sizes[0] / 256;   // 50000
    int E = in_sizes[1] / 2;     // 800000
    int P = E + n;
    const int* src = ei;
    const int* dst = ei + E;
    int NB = (n + 255) / 256;
    int HB = (E + 255) / 256;    // hist blocks
    int GX = (n + 127) / 128;    // gemm1 grid x
    int GB = GX * 2;             // gemm1 blocks

    char* p = (char*)d_ws;
    auto alloc = [&](size_t bytes) {
        void* r = (void*)p;
        p += (bytes + 255) & ~(size_t)255;
        return r;
    };
    unsigned short* h1b = (unsigned short*)alloc((size_t)n * 256 * 2);
    unsigned short* x2b = (unsigned short*)alloc((size_t)n * 256 * 2);
    unsigned short* W1t = (unsigned short*)alloc((size_t)256 * 256 * 2);
    unsigned short* W2t = (unsigned short*)alloc((size_t)16 * 256 * 2);
    float* als1 = (float*)alloc((size_t)n * 8 * 4);
    float* ald1 = (float*)alloc((size_t)n * 8 * 4);
    unsigned short* h2b = (unsigned short*)alloc((size_t)n * 16 * 2);
    float* als2 = (float*)alloc((size_t)n * 4);
    float* ald2 = (float*)alloc((size_t)n * 4);
    int* zarea = (int*)alloc((size_t)(8 * n + NB) * 4);   // deg8[8][n] + scan state[NB]
    int* deg8 = zarea;
    unsigned int* sstate = (unsigned int*)(zarea + 8 * n);
    int* offs = (int*)alloc((size_t)(n + 1) * 4);
    int* absoff = (int*)alloc((size_t)n * 8 * 4);
    int* pos = (int*)alloc((size_t)E * 4);
    int* csr = (int*)alloc((size_t)P * 4);

    hipMemsetAsync(zarea, 0, (size_t)(8 * n + NB) * 4, stream);
    k_prep<<<272, 256, 0, stream>>>(W1, W2, W1t, W2t);

    // gemm1 (+fused al1) merged with privatized hist
    k_gemm1h<<<GB + HB, 256, 0, stream>>>(x, W1t, asrc1, adst1, h1b, als1, ald1, n,
                                          dst, deg8, pos, E, GB, GX);
    k_scan<<<NB, 256, 0, stream>>>(deg8, sstate, offs, absoff, n, P);
    k_scatter<<<(P + 255) / 256, 256, 0, stream>>>(src, dst, pos, offs, absoff, csr, E, n);

    // layer-1 aggregate, split for profiling visibility
    int nh = ((n / 2) + 3) & ~3;   // 25000, multiple of 4
    k_agg1<<<(nh + 3) / 4, 256, 0, stream>>>(csr, offs, als1, ald1, h1b, b1, x2b, 0, nh);
    k_agg1<<<(n - nh + 3) / 4, 256, 0, stream>>>(csr, offs, als1, ald1, h1b, b1, x2b, nh, n);

    // layer 2
    k_gemm2<<<(n + 63) / 64, 256, 0, stream>>>(x2b, W2t, asrc2, adst2, h2b, als2, ald2, n);
    k_agg2<<<(n + 3) / 4, 256, 0, stream>>>(csr, offs, als2, ald2, h2b, b2, out, n);
}